// Round 9
// baseline (213.019 us; speedup 1.0000x reference)
//
#include <hip/hip_runtime.h>
#include <hip/hip_fp16.h>

// GCN 2-layer forward in 4 kernels:
//  K1: gemm1 (g1 = x@W1, fp16, unscaled) in parallel with edge histogram
//  K2: scan + bucket scatter + CSR finalize (196 co-resident blocks, spin barriers)
//  K3: aggregate layer1 (acc += dinv[src]*g1[src]) -> relu -> gemm2 from LDS -> g2 fp16 (pre-scaled by dinv[row])
//  K4: aggregate layer2 -> d_out
// out[v] = dinv[v]*(sum_{u in N(v)+v} dinv[u]*(xW)[u]) + b  per layer.

#define C_HID 64

static inline size_t alignup(size_t x) { return (x + 255) & ~(size_t)255; }

typedef __attribute__((address_space(3))) unsigned int lds_uint;
typedef __attribute__((address_space(1))) const unsigned int glob_uint;

// ---- block-wide inclusive scan over 256 threads ----
__device__ __forceinline__ int blockScanIncl256(int v, int* wsum) {
    const int lane = threadIdx.x & 63, wav = threadIdx.x >> 6;
    int s = v;
#pragma unroll
    for (int off = 1; off < 64; off <<= 1) {
        int t = __shfl_up(s, off);
        if (lane >= off) s += t;
    }
    if (lane == 63) wsum[wav] = s;
    __syncthreads();
    if (wav == 0 && lane < 4) {
        int ws = wsum[lane];
#pragma unroll
        for (int off = 1; off < 4; off <<= 1) {
            int t = __shfl_up(ws, off);
            if (lane >= off) ws += t;
        }
        wsum[lane] = ws;
    }
    __syncthreads();
    return (wav ? wsum[wav - 1] : 0) + s;
}

// ---- grid spin barrier (all blocks must be co-resident; grid <= 256 blocks) ----
__device__ __forceinline__ void gridbar(int* bar, int k, int nblk) {
    __syncthreads();
    if (threadIdx.x == 0) {
        __threadfence();
        atomicAdd(&bar[k], 1);
        while (atomicAdd(&bar[k], 0) < nblk) __builtin_amdgcn_s_sleep(8);
        __threadfence();
    }
    __syncthreads();
}

// ================= K1: gemm1 || hist =================
// blocks [0, nb): histogram of dst buckets (bucket = dst>>8) into S[bucket*nb + blk]
// blocks [nb, nb+ngb): 64-row tile of g1 = x @ W1 (fp16 out, NO dinv scale)
template <int K>
__global__ __launch_bounds__(256) void gemm1_hist_kernel(
    const float* __restrict__ X, const float* __restrict__ W,
    const int* __restrict__ dst, __half* __restrict__ outh,
    int* __restrict__ S, int* __restrict__ bar,
    int n, int E, int ePer, int nb) {
    constexpr int KP = K + 4;
    __shared__ float Xs[64 * KP];
    __shared__ float Ws[K * 64];
    __shared__ int h[256];
    const int t = threadIdx.x;
    const int lane = t & 63;
    const int wav = t >> 6;

    if ((int)blockIdx.x < nb) {
        // ---- hist role ----
        if (blockIdx.x == 0 && t < 8) bar[t] = 0;   // zero K2's barrier counters
        h[t] = 0;
        __syncthreads();
        int beg = blockIdx.x * ePer, end = min(E, beg + ePer);
        for (int e = beg + t; e < end; e += 256)
            atomicAdd(&h[dst[e] >> 8], 1);
        __syncthreads();
        for (int b = t; b < nb; b += 256)
            S[(size_t)b * nb + blockIdx.x] = h[b];
        return;
    }

    // ---- gemm role ----
    const int row0 = ((int)blockIdx.x - nb) * 64;
    {
        const char* gb = (const char*)W;
        char* lb = (char*)Ws;
        for (int off = wav * 1024; off < K * 64 * 4; off += 4096)
            __builtin_amdgcn_global_load_lds((glob_uint*)(gb + off + lane * 16),
                                             (lds_uint*)(lb + off), 16, 0, 0);
    }
    if (row0 + 64 <= n) {
        const float4* g4 = (const float4*)(X + (size_t)row0 * K);
        for (int i = t; i < 64 * (K / 4); i += 256) {
            float4 v = g4[i];
            int r = i / (K / 4), k0 = (i % (K / 4)) * 4;
            *(float4*)&Xs[r * KP + k0] = v;
        }
    } else {
        for (int i = t; i < 64 * K; i += 256) {
            int r = i / K, k = i % K;
            Xs[r * KP + k] = (row0 + r < n) ? X[(size_t)(row0 + r) * K + k] : 0.0f;
        }
    }
    __syncthreads();

    const int tx = t & 15;
    const int ty = t >> 4;
    float acc[4][4] = {{0.f}};
#pragma unroll 2
    for (int k0 = 0; k0 < K; k0 += 4) {
        float4 a0 = *(const float4*)&Xs[(4 * ty + 0) * KP + k0];
        float4 a1 = *(const float4*)&Xs[(4 * ty + 1) * KP + k0];
        float4 a2 = *(const float4*)&Xs[(4 * ty + 2) * KP + k0];
        float4 a3 = *(const float4*)&Xs[(4 * ty + 3) * KP + k0];
        float4 b0 = *(const float4*)&Ws[(k0 + 0) * 64 + 4 * tx];
        float4 b1 = *(const float4*)&Ws[(k0 + 1) * 64 + 4 * tx];
        float4 b2 = *(const float4*)&Ws[(k0 + 2) * 64 + 4 * tx];
        float4 b3 = *(const float4*)&Ws[(k0 + 3) * 64 + 4 * tx];
        const float* ap[4] = {(const float*)&a0, (const float*)&a1,
                              (const float*)&a2, (const float*)&a3};
        const float* bp[4] = {(const float*)&b0, (const float*)&b1,
                              (const float*)&b2, (const float*)&b3};
#pragma unroll
        for (int r = 0; r < 4; ++r)
#pragma unroll
            for (int kk = 0; kk < 4; ++kk) {
                float av = ap[r][kk];
#pragma unroll
                for (int c = 0; c < 4; ++c)
                    acc[r][c] = fmaf(av, bp[kk][c], acc[r][c]);
            }
    }
#pragma unroll
    for (int r = 0; r < 4; ++r) {
        int row = row0 + 4 * ty + r;
        if (row < n) {
            __half2 p01 = __floats2half2_rn(acc[r][0], acc[r][1]);
            __half2 p23 = __floats2half2_rn(acc[r][2], acc[r][3]);
            float2 st;
            ((__half2*)&st)[0] = p01;
            ((__half2*)&st)[1] = p23;
            *(float2*)&outh[(size_t)row * 64 + 4 * tx] = st;
        }
    }
}

// ================= K2: scan + scatter + build (one kernel, spin barriers) =================
__global__ __launch_bounds__(256) void csr_kernel(
    const int* __restrict__ src, const int* __restrict__ dst, int E, int ePer,
    int* __restrict__ S, int* __restrict__ T, int* __restrict__ bar,
    unsigned* __restrict__ ebuf, int* __restrict__ row_ptr,
    float* __restrict__ dinv, int* __restrict__ esrc, int n, int nb) {
    __shared__ int arr[256];
    __shared__ int wsum[4];
    const int b = blockIdx.x;
    const int t = threadIdx.x;

    // phase 0: exclusive scan of row b of S (counts per hist-chunk for bucket b)
    {
        int v = (t < nb) ? S[(size_t)b * nb + t] : 0;
        int incl = blockScanIncl256(v, wsum);
        int total = wsum[3];
        if (t < nb) S[(size_t)b * nb + t] = incl - v;
        if (t == 0) T[b] = total;
    }
    gridbar(bar, 0, nb);

    // phase 1: block 0 exclusive-scans bucket totals
    if (b == 0) {
        int v = (t < nb) ? T[t] : 0;
        int incl = blockScanIncl256(v, wsum);
        if (t < nb) T[t] = incl - v;
    }
    gridbar(bar, 1, nb);

    // phase 2: add bucket base to row b
    {
        int base = T[b];
        if (t < nb) S[(size_t)b * nb + t] += base;
    }
    gridbar(bar, 2, nb);

    // phase 3: scatter this block's edge chunk into bucket-grouped runs
    for (int i = t; i < nb; i += 256) arr[i] = S[(size_t)i * nb + b];  // column b
    __syncthreads();
    {
        int beg = b * ePer, end = min(E, beg + ePer);
        for (int e = beg + t; e < end; e += 256) {
            int d = dst[e];
            int s = src[e];
            int pos = atomicAdd(&arr[d >> 8], 1);            // LDS atomic
            ebuf[pos] = ((unsigned)s << 8) | (unsigned)(d & 255);
        }
    }
    gridbar(bar, 3, nb);

    // phase 4: build CSR for bucket b (256 nodes)
    const int node0 = b << 8;
    const int ebeg = S[(size_t)b * nb];
    const int eend = (b + 1 < nb) ? S[(size_t)(b + 1) * nb] : E;
    arr[t] = 0;
    __syncthreads();
    for (int e = ebeg + t; e < eend; e += 256)
        atomicAdd(&arr[ebuf[e] & 255], 1);
    __syncthreads();
    int deg = arr[t];
    int incl = blockScanIncl256(deg, wsum);
    int excl = incl - deg;
    __syncthreads();
    arr[t] = ebeg + excl;   // cursor
    int v = node0 + t;
    if (v < n) {
        row_ptr[v + 1] = ebeg + incl;
        dinv[v] = rsqrtf(1.0f + (float)deg);
        if (v == 0) row_ptr[0] = 0;
    }
    __syncthreads();
    for (int e = ebeg + t; e < eend; e += 256) {
        unsigned p = ebuf[e];
        int pos = atomicAdd(&arr[p & 255], 1);               // LDS atomic
        esrc[pos] = (int)(p >> 8);
    }
}

// ================= K3: aggregate layer1 + gemm2 (fused) =================
// 4-lane group per node: lane c owns channels c*16..c*16+15 (2x16B fp16 chunks).
// acc += dinv[src] * g1[src]; Bt = relu(dinv[v]*acc + b1); then Bt @ W2 from LDS,
// scaled by dinv[row], fp16 out.
__global__ __launch_bounds__(256) void agg1_gemm2_kernel(
    const __half* __restrict__ g1, const int* __restrict__ row_ptr,
    const int* __restrict__ esrc, const float* __restrict__ dinv,
    const float* __restrict__ b1, const float* __restrict__ W2,
    __half* __restrict__ g2, int n) {
    __shared__ float Bt[64][68];
    __shared__ float Ws2[64 * 64];
    const int t = threadIdx.x, lane = t & 63, wav = t >> 6;

    {   // stage W2 (16 KB); drains at the __syncthreads below
        const char* gb = (const char*)W2;
        char* lb = (char*)Ws2;
        for (int off = wav * 1024; off < 64 * 64 * 4; off += 4096)
            __builtin_amdgcn_global_load_lds((glob_uint*)(gb + off + lane * 16),
                                             (lds_uint*)(lb + off), 16, 0, 0);
    }

    const int g = t >> 2;          // local node 0..63
    const int c = t & 3;           // channels c*16..c*16+15
    const int row0 = blockIdx.x * 64;
    const int v = row0 + g;
    const float4* __restrict__ hs4 = (const float4*)g1;   // row = 8 float4 chunks

    if (v < n) {
        float acc[16];
        float dv0 = dinv[v];
        {   // self-loop
            size_t rb = (size_t)v * 8 + 2 * c;
            float4 r0 = hs4[rb], r1 = hs4[rb + 1];
            const __half2* h0 = (const __half2*)&r0;
            const __half2* h1 = (const __half2*)&r1;
#pragma unroll
            for (int q = 0; q < 4; ++q) {
                float2 f0 = __half22float2(h0[q]);
                float2 f1 = __half22float2(h1[q]);
                acc[2 * q] = f0.x * dv0;     acc[2 * q + 1] = f0.y * dv0;
                acc[8 + 2 * q] = f1.x * dv0; acc[9 + 2 * q] = f1.y * dv0;
            }
        }
        const int beg = row_ptr[v], end = row_ptr[v + 1];
        int j = beg;
        for (; j + 2 <= end; j += 2) {
            int s0 = esrc[j], s1 = esrc[j + 1];
            float d0 = dinv[s0], d1 = dinv[s1];
            size_t rb0 = (size_t)s0 * 8 + 2 * c, rb1 = (size_t)s1 * 8 + 2 * c;
            float4 a0 = hs4[rb0], a1 = hs4[rb0 + 1];
            float4 e0 = hs4[rb1], e1 = hs4[rb1 + 1];
            const __half2* pa0 = (const __half2*)&a0;
            const __half2* pa1 = (const __half2*)&a1;
            const __half2* pe0 = (const __half2*)&e0;
            const __half2* pe1 = (const __half2*)&e1;
#pragma unroll
            for (int q = 0; q < 4; ++q) {
                float2 f;
                f = __half22float2(pa0[q]);
                acc[2 * q] = fmaf(f.x, d0, acc[2 * q]);
                acc[2 * q + 1] = fmaf(f.y, d0, acc[2 * q + 1]);
                f = __half22float2(pa1[q]);
                acc[8 + 2 * q] = fmaf(f.x, d0, acc[8 + 2 * q]);
                acc[9 + 2 * q] = fmaf(f.y, d0, acc[9 + 2 * q]);
                f = __half22float2(pe0[q]);
                acc[2 * q] = fmaf(f.x, d1, acc[2 * q]);
                acc[2 * q + 1] = fmaf(f.y, d1, acc[2 * q + 1]);
                f = __half22float2(pe1[q]);
                acc[8 + 2 * q] = fmaf(f.x, d1, acc[8 + 2 * q]);
                acc[9 + 2 * q] = fmaf(f.y, d1, acc[9 + 2 * q]);
            }
        }
        if (j < end) {
            int s0 = esrc[j];
            float d0 = dinv[s0];
            size_t rb0 = (size_t)s0 * 8 + 2 * c;
            float4 a0 = hs4[rb0], a1 = hs4[rb0 + 1];
            const __half2* pa0 = (const __half2*)&a0;
            const __half2* pa1 = (const __half2*)&a1;
#pragma unroll
            for (int q = 0; q < 4; ++q) {
                float2 f;
                f = __half22float2(pa0[q]);
                acc[2 * q] = fmaf(f.x, d0, acc[2 * q]);
                acc[2 * q + 1] = fmaf(f.y, d0, acc[2 * q + 1]);
                f = __half22float2(pa1[q]);
                acc[8 + 2 * q] = fmaf(f.x, d0, acc[8 + 2 * q]);
                acc[9 + 2 * q] = fmaf(f.y, d0, acc[9 + 2 * q]);
            }
        }
        // Bt[g] = relu(dv0*acc + b1)
        const float* bb = b1 + c * 16;
#pragma unroll
        for (int u = 0; u < 4; ++u) {
            float4 w;
            w.x = fmaxf(fmaf(acc[4 * u + 0], dv0, bb[4 * u + 0]), 0.f);
            w.y = fmaxf(fmaf(acc[4 * u + 1], dv0, bb[4 * u + 1]), 0.f);
            w.z = fmaxf(fmaf(acc[4 * u + 2], dv0, bb[4 * u + 2]), 0.f);
            w.w = fmaxf(fmaf(acc[4 * u + 3], dv0, bb[4 * u + 3]), 0.f);
            *(float4*)&Bt[g][c * 16 + 4 * u] = w;
        }
    } else {
#pragma unroll
        for (int u = 0; u < 4; ++u)
            *(float4*)&Bt[g][c * 16 + 4 * u] = make_float4(0.f, 0.f, 0.f, 0.f);
    }
    __syncthreads();

    // gemm2 from LDS: 64x64 tile @ W2 (64x64)
    const int tx = t & 15;
    const int ty = t >> 4;
    float a2[4][4] = {{0.f}};
#pragma unroll 2
    for (int k0 = 0; k0 < 64; k0 += 4) {
        float4 x0 = *(const float4*)&Bt[4 * ty + 0][k0];
        float4 x1 = *(const float4*)&Bt[4 * ty + 1][k0];
        float4 x2 = *(const float4*)&Bt[4 * ty + 2][k0];
        float4 x3 = *(const float4*)&Bt[4 * ty + 3][k0];
        float4 w0 = *(const float4*)&Ws2[(k0 + 0) * 64 + 4 * tx];
        float4 w1 = *(const float4*)&Ws2[(k0 + 1) * 64 + 4 * tx];
        float4 w2 = *(const float4*)&Ws2[(k0 + 2) * 64 + 4 * tx];
        float4 w3 = *(const float4*)&Ws2[(k0 + 3) * 64 + 4 * tx];
        const float* xp[4] = {(const float*)&x0, (const float*)&x1,
                              (const float*)&x2, (const float*)&x3};
        const float* wp[4] = {(const float*)&w0, (const float*)&w1,
                              (const float*)&w2, (const float*)&w3};
#pragma unroll
        for (int r = 0; r < 4; ++r)
#pragma unroll
            for (int kk = 0; kk < 4; ++kk) {
                float av = xp[r][kk];
#pragma unroll
                for (int cc = 0; cc < 4; ++cc)
                    a2[r][cc] = fmaf(av, wp[kk][cc], a2[r][cc]);
            }
    }
#pragma unroll
    for (int r = 0; r < 4; ++r) {
        int row = row0 + 4 * ty + r;
        if (row < n) {
            float dv = dinv[row];
            __half2 p01 = __floats2half2_rn(a2[r][0] * dv, a2[r][1] * dv);
            __half2 p23 = __floats2half2_rn(a2[r][2] * dv, a2[r][3] * dv);
            float2 st;
            ((__half2*)&st)[0] = p01;
            ((__half2*)&st)[1] = p23;
            *(float2*)&g2[(size_t)row * 64 + 4 * tx] = st;
        }
    }
}

// ================= K4: aggregate layer2 -> d_out =================
// 8-lane group per node; g2 rows are pre-scaled by dinv[src]; unroll 4.
__global__ __launch_bounds__(256) void aggregate2_kernel(
    const __half* __restrict__ hs,
    const int* __restrict__ row_ptr,
    const int* __restrict__ esrc,
    const float* __restrict__ dinv,
    const float* __restrict__ bias,
    float* __restrict__ out, int n) {
    const int v = blockIdx.x * 32 + (threadIdx.x >> 3);
    if (v >= n) return;
    const int c8 = threadIdx.x & 7;
    const float4* __restrict__ hs4 = (const float4*)hs;

    const int beg = row_ptr[v];
    const int end = row_ptr[v + 1];

    float acc[8];
    {
        float4 raw = hs4[(size_t)v * 8 + c8];
        const __half2* hp = (const __half2*)&raw;
#pragma unroll
        for (int q = 0; q < 4; ++q) {
            float2 f = __half22float2(hp[q]);
            acc[2 * q] = f.x; acc[2 * q + 1] = f.y;
        }
    }

    int j = beg;
    for (; j + 4 <= end; j += 4) {
        int s0 = esrc[j], s1 = esrc[j + 1], s2 = esrc[j + 2], s3 = esrc[j + 3];
        float4 r0 = hs4[(size_t)s0 * 8 + c8];
        float4 r1 = hs4[(size_t)s1 * 8 + c8];
        float4 r2 = hs4[(size_t)s2 * 8 + c8];
        float4 r3 = hs4[(size_t)s3 * 8 + c8];
        const __half2* h0 = (const __half2*)&r0;
        const __half2* h1 = (const __half2*)&r1;
        const __half2* h2 = (const __half2*)&r2;
        const __half2* h3 = (const __half2*)&r3;
#pragma unroll
        for (int q = 0; q < 4; ++q) {
            float2 f0 = __half22float2(h0[q]);
            float2 f1 = __half22float2(h1[q]);
            float2 f2 = __half22float2(h2[q]);
            float2 f3 = __half22float2(h3[q]);
            acc[2 * q]     += (f0.x + f1.x) + (f2.x + f3.x);
            acc[2 * q + 1] += (f0.y + f1.y) + (f2.y + f3.y);
        }
    }
    for (; j < end; ++j) {
        int s0 = esrc[j];
        float4 r0 = hs4[(size_t)s0 * 8 + c8];
        const __half2* h0 = (const __half2*)&r0;
#pragma unroll
        for (int q = 0; q < 4; ++q) {
            float2 f0 = __half22float2(h0[q]);
            acc[2 * q] += f0.x;
            acc[2 * q + 1] += f0.y;
        }
    }

    float dv = dinv[v];
    float4 b0 = *(const float4*)(bias + c8 * 8);
    float4 b1v = *(const float4*)(bias + c8 * 8 + 4);
    float4 o0, o1;
    o0.x = fmaf(acc[0], dv, b0.x); o0.y = fmaf(acc[1], dv, b0.y);
    o0.z = fmaf(acc[2], dv, b0.z); o0.w = fmaf(acc[3], dv, b0.w);
    o1.x = fmaf(acc[4], dv, b1v.x); o1.y = fmaf(acc[5], dv, b1v.y);
    o1.z = fmaf(acc[6], dv, b1v.z); o1.w = fmaf(acc[7], dv, b1v.w);
    float4* op = (float4*)(out + (size_t)v * 64 + c8 * 8);
    op[0] = o0;
    op[1] = o1;
}

extern "C" void kernel_launch(void* const* d_in, const int* in_sizes, int n_in,
                              void* d_out, int out_size, void* d_ws, size_t ws_size,
                              hipStream_t stream) {
    const float* x  = (const float*)d_in[0];
    const int*   ei = (const int*)d_in[1];
    const float* W1 = (const float*)d_in[2];
    const float* b1 = (const float*)d_in[3];
    const float* W2 = (const float*)d_in[4];
    const float* b2 = (const float*)d_in[5];
    float* out = (float*)d_out;

    const int C_IN = 128;
    const int n = in_sizes[0] / C_IN;   // 50000 (<= 65536 required)
    const int E = in_sizes[1] / 2;      // 800000
    const int* src = ei;
    const int* dst = ei + E;

    const int nb = (n + 255) >> 8;              // 196 buckets = K2 grid (<= 256)
    const int ngb = (n + 63) / 64;              // gemm tile blocks
    const int ePer = (E + nb - 1) / nb;         // edges per hist/scatter chunk

    // Workspace: dinv | g1 | g2 | row_ptr | S+T | bar | ebuf | esrc
    char* w = (char*)d_ws;
    float*    dinv    = (float*)w;    w += alignup((size_t)n * sizeof(float));
    __half*   g1      = (__half*)w;   w += alignup((size_t)n * C_HID * sizeof(__half));
    __half*   g2      = (__half*)w;   w += alignup((size_t)n * C_HID * sizeof(__half));
    int*      row_ptr = (int*)w;      w += alignup((size_t)(n + 1) * sizeof(int));
    int*      S       = (int*)w;      w += alignup(((size_t)nb * nb + nb) * sizeof(int));
    int*      T       = S + (size_t)nb * nb;
    int*      bar     = (int*)w;      w += alignup(64 * sizeof(int));
    unsigned* ebuf    = (unsigned*)w; w += alignup((size_t)E * sizeof(unsigned));
    int*      esrc    = (int*)w;

    // K1: gemm1 || hist (hist blocks first so they start immediately)
    gemm1_hist_kernel<128><<<nb + ngb, 256, 0, stream>>>(
        x, W1, dst, g1, S, bar, n, E, ePer, nb);

    // K2: scan + scatter + build (196 co-resident blocks, spin barriers)
    csr_kernel<<<nb, 256, 0, stream>>>(
        src, dst, E, ePer, S, T, bar, ebuf, row_ptr, dinv, esrc, n, nb);

    // K3: aggregate layer1 + gemm2 fused
    agg1_gemm2_kernel<<<ngb, 256, 0, stream>>>(
        g1, row_ptr, esrc, dinv, b1, W2, g2, n);

    // K4: aggregate layer2 -> out
    aggregate2_kernel<<<(n + 31) / 32, 256, 0, stream>>>(
        g2, row_ptr, esrc, dinv, b2, out, n);
}

// Round 10
// 192.276 us; speedup vs baseline: 1.1079x; 1.1079x over previous
//
#include <hip/hip_runtime.h>
#include <hip/hip_fp16.h>

// GCN 2-layer forward in 4 kernels:
//  K1: gemm1 (g1 = x@W1, fp16, unscaled) in parallel with edge histogram
//  K2: scan + bucket scatter + CSR finalize (196 co-resident blocks, 2 light grid barriers)
//  K3: aggregate layer1 (acc += dinv[src]*g1[src]) -> relu -> gemm2 from LDS -> g2 fp16 (pre-scaled)
//  K4: aggregate layer2 -> d_out

#define C_HID 64

static inline size_t alignup(size_t x) { return (x + 255) & ~(size_t)255; }

typedef __attribute__((address_space(3))) unsigned int lds_uint;
typedef __attribute__((address_space(1))) const unsigned int glob_uint;

// ---- block-wide inclusive scan over 256 threads ----
__device__ __forceinline__ int blockScanIncl256(int v, int* wsum) {
    const int lane = threadIdx.x & 63, wav = threadIdx.x >> 6;
    int s = v;
#pragma unroll
    for (int off = 1; off < 64; off <<= 1) {
        int t = __shfl_up(s, off);
        if (lane >= off) s += t;
    }
    if (lane == 63) wsum[wav] = s;
    __syncthreads();
    if (wav == 0 && lane < 4) {
        int ws = wsum[lane];
#pragma unroll
        for (int off = 1; off < 4; off <<= 1) {
            int t = __shfl_up(ws, off);
            if (lane >= off) ws += t;
        }
        wsum[lane] = ws;
    }
    __syncthreads();
    return (wav ? wsum[wav - 1] : 0) + s;
}

// ---- grid spin barrier: coherent-load polling (no RMW storm) ----
__device__ __forceinline__ void gridbar(int* bar, int k, int nblk) {
    __syncthreads();
    if (threadIdx.x == 0) {
        __threadfence();   // release: L2 writeback
        __hip_atomic_fetch_add(&bar[k], 1, __ATOMIC_RELEASE, __HIP_MEMORY_SCOPE_AGENT);
        while (__hip_atomic_load(&bar[k], __ATOMIC_RELAXED, __HIP_MEMORY_SCOPE_AGENT) < nblk)
            __builtin_amdgcn_s_sleep(2);
        __threadfence();   // acquire: L2 invalidate
    }
    __syncthreads();
}

// ================= K1: gemm1 || hist =================
template <int K>
__global__ __launch_bounds__(256) void gemm1_hist_kernel(
    const float* __restrict__ X, const float* __restrict__ W,
    const int* __restrict__ dst, __half* __restrict__ outh,
    int* __restrict__ S, int* __restrict__ bar,
    int n, int E, int ePer, int nb) {
    constexpr int KP = K + 4;
    __shared__ float Xs[64 * KP];
    __shared__ float Ws[K * 64];
    __shared__ int h[256];
    const int t = threadIdx.x;
    const int lane = t & 63;
    const int wav = t >> 6;

    if ((int)blockIdx.x < nb) {
        if (blockIdx.x == 0 && t < 8) bar[t] = 0;   // zero K2's barrier counters
        h[t] = 0;
        __syncthreads();
        int beg = blockIdx.x * ePer, end = min(E, beg + ePer);
        for (int e = beg + t; e < end; e += 256)
            atomicAdd(&h[dst[e] >> 8], 1);
        __syncthreads();
        for (int b = t; b < nb; b += 256)
            S[(size_t)b * nb + blockIdx.x] = h[b];
        return;
    }

    const int row0 = ((int)blockIdx.x - nb) * 64;
    {
        const char* gb = (const char*)W;
        char* lb = (char*)Ws;
        for (int off = wav * 1024; off < K * 64 * 4; off += 4096)
            __builtin_amdgcn_global_load_lds((glob_uint*)(gb + off + lane * 16),
                                             (lds_uint*)(lb + off), 16, 0, 0);
    }
    if (row0 + 64 <= n) {
        const float4* g4 = (const float4*)(X + (size_t)row0 * K);
        for (int i = t; i < 64 * (K / 4); i += 256) {
            float4 v = g4[i];
            int r = i / (K / 4), k0 = (i % (K / 4)) * 4;
            *(float4*)&Xs[r * KP + k0] = v;
        }
    } else {
        for (int i = t; i < 64 * K; i += 256) {
            int r = i / K, k = i % K;
            Xs[r * KP + k] = (row0 + r < n) ? X[(size_t)(row0 + r) * K + k] : 0.0f;
        }
    }
    __syncthreads();

    const int tx = t & 15;
    const int ty = t >> 4;
    float acc[4][4] = {{0.f}};
#pragma unroll 2
    for (int k0 = 0; k0 < K; k0 += 4) {
        float4 a0 = *(const float4*)&Xs[(4 * ty + 0) * KP + k0];
        float4 a1 = *(const float4*)&Xs[(4 * ty + 1) * KP + k0];
        float4 a2 = *(const float4*)&Xs[(4 * ty + 2) * KP + k0];
        float4 a3 = *(const float4*)&Xs[(4 * ty + 3) * KP + k0];
        float4 b0 = *(const float4*)&Ws[(k0 + 0) * 64 + 4 * tx];
        float4 b1 = *(const float4*)&Ws[(k0 + 1) * 64 + 4 * tx];
        float4 b2 = *(const float4*)&Ws[(k0 + 2) * 64 + 4 * tx];
        float4 b3 = *(const float4*)&Ws[(k0 + 3) * 64 + 4 * tx];
        const float* ap[4] = {(const float*)&a0, (const float*)&a1,
                              (const float*)&a2, (const float*)&a3};
        const float* bp[4] = {(const float*)&b0, (const float*)&b1,
                              (const float*)&b2, (const float*)&b3};
#pragma unroll
        for (int r = 0; r < 4; ++r)
#pragma unroll
            for (int kk = 0; kk < 4; ++kk) {
                float av = ap[r][kk];
#pragma unroll
                for (int c = 0; c < 4; ++c)
                    acc[r][c] = fmaf(av, bp[kk][c], acc[r][c]);
            }
    }
#pragma unroll
    for (int r = 0; r < 4; ++r) {
        int row = row0 + 4 * ty + r;
        if (row < n) {
            __half2 p01 = __floats2half2_rn(acc[r][0], acc[r][1]);
            __half2 p23 = __floats2half2_rn(acc[r][2], acc[r][3]);
            float2 st;
            ((__half2*)&st)[0] = p01;
            ((__half2*)&st)[1] = p23;
            *(float2*)&outh[(size_t)row * 64 + 4 * tx] = st;
        }
    }
}

// ================= K2: scan + scatter + build (2 grid barriers) =================
__global__ __launch_bounds__(256) void csr_kernel(
    const int* __restrict__ src, const int* __restrict__ dst, int E, int ePer,
    int* __restrict__ S, int* __restrict__ T, int* __restrict__ bar,
    unsigned* __restrict__ ebuf, int* __restrict__ row_ptr,
    float* __restrict__ dinv, int* __restrict__ esrc, int n, int nb) {
    __shared__ int arr[256];
    __shared__ int texcl[256];
    __shared__ int wsum[4];
    const int b = blockIdx.x;
    const int t = threadIdx.x;

    // phase 0: exclusive scan of row b of S; T[b] = row total
    {
        int v = (t < nb) ? S[(size_t)b * nb + t] : 0;
        int incl = blockScanIncl256(v, wsum);
        if (t < nb) S[(size_t)b * nb + t] = incl - v;
        if (t == 0) T[b] = wsum[3];
    }
    gridbar(bar, 0, nb);   // S rows scanned, T totals visible

    // phase 1 (redundant per block): texcl = exclusive scan of T
    {
        int v = (t < nb) ? T[t] : 0;
        int incl = blockScanIncl256(v, wsum);
        texcl[t] = incl - v;
    }
    __syncthreads();

    // phase 2: scatter this block's edge chunk; cursor = bucket base + intra offset
    if (t < nb) arr[t] = S[(size_t)t * nb + b] + texcl[t];
    __syncthreads();
    {
        int beg = b * ePer, end = min(E, beg + ePer);
        for (int e = beg + t; e < end; e += 256) {
            int d = dst[e];
            int s = src[e];
            int pos = atomicAdd(&arr[d >> 8], 1);            // LDS atomic
            ebuf[pos] = ((unsigned)s << 8) | (unsigned)(d & 255);
        }
    }
    gridbar(bar, 1, nb);   // ebuf complete

    // phase 3: build CSR for bucket b (256 nodes)
    const int node0 = b << 8;
    const int ebeg = texcl[b];
    const int eend = (b + 1 < nb) ? texcl[b + 1] : E;
    arr[t] = 0;
    __syncthreads();
    for (int e = ebeg + t; e < eend; e += 256)
        atomicAdd(&arr[ebuf[e] & 255], 1);
    __syncthreads();
    int deg = arr[t];
    int incl = blockScanIncl256(deg, wsum);
    int excl = incl - deg;
    __syncthreads();
    arr[t] = ebeg + excl;   // cursor
    int v = node0 + t;
    if (v < n) {
        row_ptr[v + 1] = ebeg + incl;
        dinv[v] = rsqrtf(1.0f + (float)deg);
        if (v == 0) row_ptr[0] = 0;
    }
    __syncthreads();
    for (int e = ebeg + t; e < eend; e += 256) {
        unsigned p = ebuf[e];
        int pos = atomicAdd(&arr[p & 255], 1);               // LDS atomic
        esrc[pos] = (int)(p >> 8);
    }
}

// ================= K3: aggregate layer1 + gemm2 (fused) =================
__global__ __launch_bounds__(256) void agg1_gemm2_kernel(
    const __half* __restrict__ g1, const int* __restrict__ row_ptr,
    const int* __restrict__ esrc, const float* __restrict__ dinv,
    const float* __restrict__ b1, const float* __restrict__ W2,
    __half* __restrict__ g2, int n) {
    __shared__ float Bt[64][68];
    __shared__ float Ws2[64 * 64];
    const int t = threadIdx.x, lane = t & 63, wav = t >> 6;

    {
        const char* gb = (const char*)W2;
        char* lb = (char*)Ws2;
        for (int off = wav * 1024; off < 64 * 64 * 4; off += 4096)
            __builtin_amdgcn_global_load_lds((glob_uint*)(gb + off + lane * 16),
                                             (lds_uint*)(lb + off), 16, 0, 0);
    }

    const int g = t >> 2;
    const int c = t & 3;
    const int row0 = blockIdx.x * 64;
    const int v = row0 + g;
    const float4* __restrict__ hs4 = (const float4*)g1;

    if (v < n) {
        float acc[16];
        float dv0 = dinv[v];
        {
            size_t rb = (size_t)v * 8 + 2 * c;
            float4 r0 = hs4[rb], r1 = hs4[rb + 1];
            const __half2* h0 = (const __half2*)&r0;
            const __half2* h1 = (const __half2*)&r1;
#pragma unroll
            for (int q = 0; q < 4; ++q) {
                float2 f0 = __half22float2(h0[q]);
                float2 f1 = __half22float2(h1[q]);
                acc[2 * q] = f0.x * dv0;     acc[2 * q + 1] = f0.y * dv0;
                acc[8 + 2 * q] = f1.x * dv0; acc[9 + 2 * q] = f1.y * dv0;
            }
        }
        const int beg = row_ptr[v], end = row_ptr[v + 1];
        int j = beg;
        for (; j + 2 <= end; j += 2) {
            int s0 = esrc[j], s1 = esrc[j + 1];
            float d0 = dinv[s0], d1 = dinv[s1];
            size_t rb0 = (size_t)s0 * 8 + 2 * c, rb1 = (size_t)s1 * 8 + 2 * c;
            float4 a0 = hs4[rb0], a1 = hs4[rb0 + 1];
            float4 e0 = hs4[rb1], e1 = hs4[rb1 + 1];
            const __half2* pa0 = (const __half2*)&a0;
            const __half2* pa1 = (const __half2*)&a1;
            const __half2* pe0 = (const __half2*)&e0;
            const __half2* pe1 = (const __half2*)&e1;
#pragma unroll
            for (int q = 0; q < 4; ++q) {
                float2 f;
                f = __half22float2(pa0[q]);
                acc[2 * q] = fmaf(f.x, d0, acc[2 * q]);
                acc[2 * q + 1] = fmaf(f.y, d0, acc[2 * q + 1]);
                f = __half22float2(pa1[q]);
                acc[8 + 2 * q] = fmaf(f.x, d0, acc[8 + 2 * q]);
                acc[9 + 2 * q] = fmaf(f.y, d0, acc[9 + 2 * q]);
                f = __half22float2(pe0[q]);
                acc[2 * q] = fmaf(f.x, d1, acc[2 * q]);
                acc[2 * q + 1] = fmaf(f.y, d1, acc[2 * q + 1]);
                f = __half22float2(pe1[q]);
                acc[8 + 2 * q] = fmaf(f.x, d1, acc[8 + 2 * q]);
                acc[9 + 2 * q] = fmaf(f.y, d1, acc[9 + 2 * q]);
            }
        }
        if (j < end) {
            int s0 = esrc[j];
            float d0 = dinv[s0];
            size_t rb0 = (size_t)s0 * 8 + 2 * c;
            float4 a0 = hs4[rb0], a1 = hs4[rb0 + 1];
            const __half2* pa0 = (const __half2*)&a0;
            const __half2* pa1 = (const __half2*)&a1;
#pragma unroll
            for (int q = 0; q < 4; ++q) {
                float2 f;
                f = __half22float2(pa0[q]);
                acc[2 * q] = fmaf(f.x, d0, acc[2 * q]);
                acc[2 * q + 1] = fmaf(f.y, d0, acc[2 * q + 1]);
                f = __half22float2(pa1[q]);
                acc[8 + 2 * q] = fmaf(f.x, d0, acc[8 + 2 * q]);
                acc[9 + 2 * q] = fmaf(f.y, d0, acc[9 + 2 * q]);
            }
        }
        const float* bb = b1 + c * 16;
#pragma unroll
        for (int u = 0; u < 4; ++u) {
            float4 w;
            w.x = fmaxf(fmaf(acc[4 * u + 0], dv0, bb[4 * u + 0]), 0.f);
            w.y = fmaxf(fmaf(acc[4 * u + 1], dv0, bb[4 * u + 1]), 0.f);
            w.z = fmaxf(fmaf(acc[4 * u + 2], dv0, bb[4 * u + 2]), 0.f);
            w.w = fmaxf(fmaf(acc[4 * u + 3], dv0, bb[4 * u + 3]), 0.f);
            *(float4*)&Bt[g][c * 16 + 4 * u] = w;
        }
    } else {
#pragma unroll
        for (int u = 0; u < 4; ++u)
            *(float4*)&Bt[g][c * 16 + 4 * u] = make_float4(0.f, 0.f, 0.f, 0.f);
    }
    __syncthreads();

    const int tx = t & 15;
    const int ty = t >> 4;
    float a2[4][4] = {{0.f}};
#pragma unroll 2
    for (int k0 = 0; k0 < 64; k0 += 4) {
        float4 x0 = *(const float4*)&Bt[4 * ty + 0][k0];
        float4 x1 = *(const float4*)&Bt[4 * ty + 1][k0];
        float4 x2 = *(const float4*)&Bt[4 * ty + 2][k0];
        float4 x3 = *(const float4*)&Bt[4 * ty + 3][k0];
        float4 w0 = *(const float4*)&Ws2[(k0 + 0) * 64 + 4 * tx];
        float4 w1 = *(const float4*)&Ws2[(k0 + 1) * 64 + 4 * tx];
        float4 w2 = *(const float4*)&Ws2[(k0 + 2) * 64 + 4 * tx];
        float4 w3 = *(const float4*)&Ws2[(k0 + 3) * 64 + 4 * tx];
        const float* xp[4] = {(const float*)&x0, (const float*)&x1,
                              (const float*)&x2, (const float*)&x3};
        const float* wp[4] = {(const float*)&w0, (const float*)&w1,
                              (const float*)&w2, (const float*)&w3};
#pragma unroll
        for (int r = 0; r < 4; ++r)
#pragma unroll
            for (int kk = 0; kk < 4; ++kk) {
                float av = xp[r][kk];
#pragma unroll
                for (int cc = 0; cc < 4; ++cc)
                    a2[r][cc] = fmaf(av, wp[kk][cc], a2[r][cc]);
            }
    }
#pragma unroll
    for (int r = 0; r < 4; ++r) {
        int row = row0 + 4 * ty + r;
        if (row < n) {
            float dv = dinv[row];
            __half2 p01 = __floats2half2_rn(a2[r][0] * dv, a2[r][1] * dv);
            __half2 p23 = __floats2half2_rn(a2[r][2] * dv, a2[r][3] * dv);
            float2 st;
            ((__half2*)&st)[0] = p01;
            ((__half2*)&st)[1] = p23;
            *(float2*)&g2[(size_t)row * 64 + 4 * tx] = st;
        }
    }
}

// ================= K4: aggregate layer2 -> d_out =================
__global__ __launch_bounds__(256) void aggregate2_kernel(
    const __half* __restrict__ hs,
    const int* __restrict__ row_ptr,
    const int* __restrict__ esrc,
    const float* __restrict__ dinv,
    const float* __restrict__ bias,
    float* __restrict__ out, int n) {
    const int v = blockIdx.x * 32 + (threadIdx.x >> 3);
    if (v >= n) return;
    const int c8 = threadIdx.x & 7;
    const float4* __restrict__ hs4 = (const float4*)hs;

    const int beg = row_ptr[v];
    const int end = row_ptr[v + 1];

    float acc[8];
    {
        float4 raw = hs4[(size_t)v * 8 + c8];
        const __half2* hp = (const __half2*)&raw;
#pragma unroll
        for (int q = 0; q < 4; ++q) {
            float2 f = __half22float2(hp[q]);
            acc[2 * q] = f.x; acc[2 * q + 1] = f.y;
        }
    }

    int j = beg;
    for (; j + 4 <= end; j += 4) {
        int s0 = esrc[j], s1 = esrc[j + 1], s2 = esrc[j + 2], s3 = esrc[j + 3];
        float4 r0 = hs4[(size_t)s0 * 8 + c8];
        float4 r1 = hs4[(size_t)s1 * 8 + c8];
        float4 r2 = hs4[(size_t)s2 * 8 + c8];
        float4 r3 = hs4[(size_t)s3 * 8 + c8];
        const __half2* h0 = (const __half2*)&r0;
        const __half2* h1 = (const __half2*)&r1;
        const __half2* h2 = (const __half2*)&r2;
        const __half2* h3 = (const __half2*)&r3;
#pragma unroll
        for (int q = 0; q < 4; ++q) {
            float2 f0 = __half22float2(h0[q]);
            float2 f1 = __half22float2(h1[q]);
            float2 f2 = __half22float2(h2[q]);
            float2 f3 = __half22float2(h3[q]);
            acc[2 * q]     += (f0.x + f1.x) + (f2.x + f3.x);
            acc[2 * q + 1] += (f0.y + f1.y) + (f2.y + f3.y);
        }
    }
    for (; j < end; ++j) {
        int s0 = esrc[j];
        float4 r0 = hs4[(size_t)s0 * 8 + c8];
        const __half2* h0 = (const __half2*)&r0;
#pragma unroll
        for (int q = 0; q < 4; ++q) {
            float2 f0 = __half22float2(h0[q]);
            acc[2 * q] += f0.x;
            acc[2 * q + 1] += f0.y;
        }
    }

    float dv = dinv[v];
    float4 b0 = *(const float4*)(bias + c8 * 8);
    float4 b1v = *(const float4*)(bias + c8 * 8 + 4);
    float4 o0, o1;
    o0.x = fmaf(acc[0], dv, b0.x); o0.y = fmaf(acc[1], dv, b0.y);
    o0.z = fmaf(acc[2], dv, b0.z); o0.w = fmaf(acc[3], dv, b0.w);
    o1.x = fmaf(acc[4], dv, b1v.x); o1.y = fmaf(acc[5], dv, b1v.y);
    o1.z = fmaf(acc[6], dv, b1v.z); o1.w = fmaf(acc[7], dv, b1v.w);
    float4* op = (float4*)(out + (size_t)v * 64 + c8 * 8);
    op[0] = o0;
    op[1] = o1;
}

extern "C" void kernel_launch(void* const* d_in, const int* in_sizes, int n_in,
                              void* d_out, int out_size, void* d_ws, size_t ws_size,
                              hipStream_t stream) {
    const float* x  = (const float*)d_in[0];
    const int*   ei = (const int*)d_in[1];
    const float* W1 = (const float*)d_in[2];
    const float* b1 = (const float*)d_in[3];
    const float* W2 = (const float*)d_in[4];
    const float* b2 = (const float*)d_in[5];
    float* out = (float*)d_out;

    const int C_IN = 128;
    const int n = in_sizes[0] / C_IN;   // 50000 (<= 65536 required)
    const int E = in_sizes[1] / 2;      // 800000
    const int* src = ei;
    const int* dst = ei + E;

    const int nb = (n + 255) >> 8;              // 196 buckets = K2 grid (<= 256)
    const int ngb = (n + 63) / 64;              // gemm tile blocks
    const int ePer = (E + nb - 1) / nb;         // edges per hist/scatter chunk

    // Workspace: dinv | g1 | g2 | row_ptr | S+T | bar | ebuf | esrc
    char* w = (char*)d_ws;
    float*    dinv    = (float*)w;    w += alignup((size_t)n * sizeof(float));
    __half*   g1      = (__half*)w;   w += alignup((size_t)n * C_HID * sizeof(__half));
    __half*   g2      = (__half*)w;   w += alignup((size_t)n * C_HID * sizeof(__half));
    int*      row_ptr = (int*)w;      w += alignup((size_t)(n + 1) * sizeof(int));
    int*      S       = (int*)w;      w += alignup(((size_t)nb * nb + nb) * sizeof(int));
    int*      T       = S + (size_t)nb * nb;
    int*      bar     = (int*)w;      w += alignup(64 * sizeof(int));
    unsigned* ebuf    = (unsigned*)w; w += alignup((size_t)E * sizeof(unsigned));
    int*      esrc    = (int*)w;

    // K1: gemm1 || hist
    gemm1_hist_kernel<128><<<nb + ngb, 256, 0, stream>>>(
        x, W1, dst, g1, S, bar, n, E, ePer, nb);

    // K2: scan + scatter + build (2 light grid barriers)
    csr_kernel<<<nb, 256, 0, stream>>>(
        src, dst, E, ePer, S, T, bar, ebuf, row_ptr, dinv, esrc, n, nb);

    // K3: aggregate layer1 + gemm2 fused
    agg1_gemm2_kernel<<<ngb, 256, 0, stream>>>(
        g1, row_ptr, esrc, dinv, b1, W2, g2, n);

    // K4: aggregate layer2 -> out
    aggregate2_kernel<<<(n + 31) / 32, 256, 0, stream>>>(
        g2, row_ptr, esrc, dinv, b2, out, n);
}

// Round 11
// 162.407 us; speedup vs baseline: 1.3116x; 1.1839x over previous
//
#include <hip/hip_runtime.h>
#include <hip/hip_fp16.h>

// GCN 2-layer forward in 7 kernels:
//  K1 : gemm1 (g1 = x@W1, fp16, unscaled) in parallel with edge histogram
//  K2a: per-bucket row scan of S (196 blocks)       K2b: scan of bucket totals T (1 block)
//  K2c: bucket scatter (196 blocks, LDS cursors)    K2d: per-bucket CSR finalize (196 blocks)
//  K3 : aggregate layer1 (acc += dinv[src]*g1[src]) -> relu -> gemm2 from LDS -> g2 fp16 (pre-scaled)
//  K4 : aggregate layer2 -> d_out

#define C_HID 64

static inline size_t alignup(size_t x) { return (x + 255) & ~(size_t)255; }

typedef __attribute__((address_space(3))) unsigned int lds_uint;
typedef __attribute__((address_space(1))) const unsigned int glob_uint;

// ---- block-wide inclusive scan over 256 threads ----
__device__ __forceinline__ int blockScanIncl256(int v, int* wsum) {
    const int lane = threadIdx.x & 63, wav = threadIdx.x >> 6;
    int s = v;
#pragma unroll
    for (int off = 1; off < 64; off <<= 1) {
        int t = __shfl_up(s, off);
        if (lane >= off) s += t;
    }
    if (lane == 63) wsum[wav] = s;
    __syncthreads();
    if (wav == 0 && lane < 4) {
        int ws = wsum[lane];
#pragma unroll
        for (int off = 1; off < 4; off <<= 1) {
            int t = __shfl_up(ws, off);
            if (lane >= off) ws += t;
        }
        wsum[lane] = ws;
    }
    __syncthreads();
    return (wav ? wsum[wav - 1] : 0) + s;
}

// ================= K1: gemm1 || hist =================
template <int K>
__global__ __launch_bounds__(256) void gemm1_hist_kernel(
    const float* __restrict__ X, const float* __restrict__ W,
    const int* __restrict__ dst, __half* __restrict__ outh,
    int* __restrict__ S, int n, int E, int ePer, int nb) {
    constexpr int KP = K + 4;
    __shared__ float Xs[64 * KP];
    __shared__ float Ws[K * 64];
    __shared__ int h[256];
    const int t = threadIdx.x;
    const int lane = t & 63;
    const int wav = t >> 6;

    if ((int)blockIdx.x < nb) {
        h[t] = 0;
        __syncthreads();
        int beg = blockIdx.x * ePer, end = min(E, beg + ePer);
        for (int e = beg + t; e < end; e += 256)
            atomicAdd(&h[dst[e] >> 8], 1);
        __syncthreads();
        for (int b = t; b < nb; b += 256)
            S[(size_t)b * nb + blockIdx.x] = h[b];
        return;
    }

    const int row0 = ((int)blockIdx.x - nb) * 64;
    {
        const char* gb = (const char*)W;
        char* lb = (char*)Ws;
        for (int off = wav * 1024; off < K * 64 * 4; off += 4096)
            __builtin_amdgcn_global_load_lds((glob_uint*)(gb + off + lane * 16),
                                             (lds_uint*)(lb + off), 16, 0, 0);
    }
    if (row0 + 64 <= n) {
        const float4* g4 = (const float4*)(X + (size_t)row0 * K);
        for (int i = t; i < 64 * (K / 4); i += 256) {
            float4 v = g4[i];
            int r = i / (K / 4), k0 = (i % (K / 4)) * 4;
            *(float4*)&Xs[r * KP + k0] = v;
        }
    } else {
        for (int i = t; i < 64 * K; i += 256) {
            int r = i / K, k = i % K;
            Xs[r * KP + k] = (row0 + r < n) ? X[(size_t)(row0 + r) * K + k] : 0.0f;
        }
    }
    __syncthreads();

    const int tx = t & 15;
    const int ty = t >> 4;
    float acc[4][4] = {{0.f}};
#pragma unroll 2
    for (int k0 = 0; k0 < K; k0 += 4) {
        float4 a0 = *(const float4*)&Xs[(4 * ty + 0) * KP + k0];
        float4 a1 = *(const float4*)&Xs[(4 * ty + 1) * KP + k0];
        float4 a2 = *(const float4*)&Xs[(4 * ty + 2) * KP + k0];
        float4 a3 = *(const float4*)&Xs[(4 * ty + 3) * KP + k0];
        float4 b0 = *(const float4*)&Ws[(k0 + 0) * 64 + 4 * tx];
        float4 b1 = *(const float4*)&Ws[(k0 + 1) * 64 + 4 * tx];
        float4 b2 = *(const float4*)&Ws[(k0 + 2) * 64 + 4 * tx];
        float4 b3 = *(const float4*)&Ws[(k0 + 3) * 64 + 4 * tx];
        const float* ap[4] = {(const float*)&a0, (const float*)&a1,
                              (const float*)&a2, (const float*)&a3};
        const float* bp[4] = {(const float*)&b0, (const float*)&b1,
                              (const float*)&b2, (const float*)&b3};
#pragma unroll
        for (int r = 0; r < 4; ++r)
#pragma unroll
            for (int kk = 0; kk < 4; ++kk) {
                float av = ap[r][kk];
#pragma unroll
                for (int c = 0; c < 4; ++c)
                    acc[r][c] = fmaf(av, bp[kk][c], acc[r][c]);
            }
    }
#pragma unroll
    for (int r = 0; r < 4; ++r) {
        int row = row0 + 4 * ty + r;
        if (row < n) {
            __half2 p01 = __floats2half2_rn(acc[r][0], acc[r][1]);
            __half2 p23 = __floats2half2_rn(acc[r][2], acc[r][3]);
            float2 st;
            ((__half2*)&st)[0] = p01;
            ((__half2*)&st)[1] = p23;
            *(float2*)&outh[(size_t)row * 64 + 4 * tx] = st;
        }
    }
}

// ================= K2a: exclusive scan of each bucket-row of S; T[b] = row total ====
__global__ __launch_bounds__(256) void scan_rows_kernel(
    int* __restrict__ S, int* __restrict__ T, int nb) {
    __shared__ int wsum[4];
    const int b = blockIdx.x, t = threadIdx.x;
    int v = (t < nb) ? S[(size_t)b * nb + t] : 0;
    int incl = blockScanIncl256(v, wsum);
    if (t < nb) S[(size_t)b * nb + t] = incl - v;
    if (t == 0) T[b] = wsum[3];
}

// ================= K2b: exclusive scan of T (one block); T[nb] = E ================
__global__ __launch_bounds__(256) void scan_T_kernel(int* __restrict__ T, int nb) {
    __shared__ int wsum[4];
    const int t = threadIdx.x;
    int v = (t < nb) ? T[t] : 0;
    int incl = blockScanIncl256(v, wsum);
    if (t < nb) T[t] = incl - v;
    if (t == nb - 1) T[nb] = incl;   // total
}

// ================= K2c: bucket scatter =================
__global__ __launch_bounds__(256) void scatter_kernel(
    const int* __restrict__ src, const int* __restrict__ dst, int E, int ePer,
    const int* __restrict__ S, const int* __restrict__ T,
    unsigned* __restrict__ ebuf, int nb) {
    __shared__ int arr[256];
    const int b = blockIdx.x, t = threadIdx.x;
    if (t < nb) arr[t] = S[(size_t)t * nb + b] + T[t];
    __syncthreads();
    int beg = b * ePer, end = min(E, beg + ePer);
    for (int e = beg + t; e < end; e += 256) {
        int d = dst[e];
        int s = src[e];
        int pos = atomicAdd(&arr[d >> 8], 1);            // LDS atomic
        ebuf[pos] = ((unsigned)s << 8) | (unsigned)(d & 255);
    }
}

// ================= K2d: per-bucket CSR finalize =================
__global__ __launch_bounds__(256) void build_kernel(
    const unsigned* __restrict__ ebuf, const int* __restrict__ T,
    int* __restrict__ row_ptr, float* __restrict__ dinv,
    int* __restrict__ esrc, int n, int nb) {
    __shared__ int arr[256];
    __shared__ int wsum[4];
    const int b = blockIdx.x, t = threadIdx.x;
    const int node0 = b << 8;
    const int ebeg = T[b];
    const int eend = T[b + 1];

    arr[t] = 0;
    __syncthreads();
    for (int e = ebeg + t; e < eend; e += 256)
        atomicAdd(&arr[ebuf[e] & 255], 1);
    __syncthreads();
    int deg = arr[t];
    int incl = blockScanIncl256(deg, wsum);
    int excl = incl - deg;
    __syncthreads();
    arr[t] = ebeg + excl;   // cursor
    int v = node0 + t;
    if (v < n) {
        row_ptr[v + 1] = ebeg + incl;
        dinv[v] = rsqrtf(1.0f + (float)deg);
        if (v == 0) row_ptr[0] = 0;
    }
    __syncthreads();
    for (int e = ebeg + t; e < eend; e += 256) {
        unsigned p = ebuf[e];
        int pos = atomicAdd(&arr[p & 255], 1);           // LDS atomic
        esrc[pos] = (int)(p >> 8);
    }
}

// ================= K3: aggregate layer1 + gemm2 (fused) =================
__global__ __launch_bounds__(256) void agg1_gemm2_kernel(
    const __half* __restrict__ g1, const int* __restrict__ row_ptr,
    const int* __restrict__ esrc, const float* __restrict__ dinv,
    const float* __restrict__ b1, const float* __restrict__ W2,
    __half* __restrict__ g2, int n) {
    __shared__ float Bt[64][68];
    __shared__ float Ws2[64 * 64];
    const int t = threadIdx.x, lane = t & 63, wav = t >> 6;

    {
        const char* gb = (const char*)W2;
        char* lb = (char*)Ws2;
        for (int off = wav * 1024; off < 64 * 64 * 4; off += 4096)
            __builtin_amdgcn_global_load_lds((glob_uint*)(gb + off + lane * 16),
                                             (lds_uint*)(lb + off), 16, 0, 0);
    }

    const int g = t >> 2;
    const int c = t & 3;
    const int row0 = blockIdx.x * 64;
    const int v = row0 + g;
    const float4* __restrict__ hs4 = (const float4*)g1;

    if (v < n) {
        float acc[16];
        float dv0 = dinv[v];
        {
            size_t rb = (size_t)v * 8 + 2 * c;
            float4 r0 = hs4[rb], r1 = hs4[rb + 1];
            const __half2* h0 = (const __half2*)&r0;
            const __half2* h1 = (const __half2*)&r1;
#pragma unroll
            for (int q = 0; q < 4; ++q) {
                float2 f0 = __half22float2(h0[q]);
                float2 f1 = __half22float2(h1[q]);
                acc[2 * q] = f0.x * dv0;     acc[2 * q + 1] = f0.y * dv0;
                acc[8 + 2 * q] = f1.x * dv0; acc[9 + 2 * q] = f1.y * dv0;
            }
        }
        const int beg = row_ptr[v], end = row_ptr[v + 1];
        int j = beg;
        for (; j + 2 <= end; j += 2) {
            int s0 = esrc[j], s1 = esrc[j + 1];
            float d0 = dinv[s0], d1 = dinv[s1];
            size_t rb0 = (size_t)s0 * 8 + 2 * c, rb1 = (size_t)s1 * 8 + 2 * c;
            float4 a0 = hs4[rb0], a1 = hs4[rb0 + 1];
            float4 e0 = hs4[rb1], e1 = hs4[rb1 + 1];
            const __half2* pa0 = (const __half2*)&a0;
            const __half2* pa1 = (const __half2*)&a1;
            const __half2* pe0 = (const __half2*)&e0;
            const __half2* pe1 = (const __half2*)&e1;
#pragma unroll
            for (int q = 0; q < 4; ++q) {
                float2 f;
                f = __half22float2(pa0[q]);
                acc[2 * q] = fmaf(f.x, d0, acc[2 * q]);
                acc[2 * q + 1] = fmaf(f.y, d0, acc[2 * q + 1]);
                f = __half22float2(pa1[q]);
                acc[8 + 2 * q] = fmaf(f.x, d0, acc[8 + 2 * q]);
                acc[9 + 2 * q] = fmaf(f.y, d0, acc[9 + 2 * q]);
                f = __half22float2(pe0[q]);
                acc[2 * q] = fmaf(f.x, d1, acc[2 * q]);
                acc[2 * q + 1] = fmaf(f.y, d1, acc[2 * q + 1]);
                f = __half22float2(pe1[q]);
                acc[8 + 2 * q] = fmaf(f.x, d1, acc[8 + 2 * q]);
                acc[9 + 2 * q] = fmaf(f.y, d1, acc[9 + 2 * q]);
            }
        }
        if (j < end) {
            int s0 = esrc[j];
            float d0 = dinv[s0];
            size_t rb0 = (size_t)s0 * 8 + 2 * c;
            float4 a0 = hs4[rb0], a1 = hs4[rb0 + 1];
            const __half2* pa0 = (const __half2*)&a0;
            const __half2* pa1 = (const __half2*)&a1;
#pragma unroll
            for (int q = 0; q < 4; ++q) {
                float2 f;
                f = __half22float2(pa0[q]);
                acc[2 * q] = fmaf(f.x, d0, acc[2 * q]);
                acc[2 * q + 1] = fmaf(f.y, d0, acc[2 * q + 1]);
                f = __half22float2(pa1[q]);
                acc[8 + 2 * q] = fmaf(f.x, d0, acc[8 + 2 * q]);
                acc[9 + 2 * q] = fmaf(f.y, d0, acc[9 + 2 * q]);
            }
        }
        const float* bb = b1 + c * 16;
#pragma unroll
        for (int u = 0; u < 4; ++u) {
            float4 w;
            w.x = fmaxf(fmaf(acc[4 * u + 0], dv0, bb[4 * u + 0]), 0.f);
            w.y = fmaxf(fmaf(acc[4 * u + 1], dv0, bb[4 * u + 1]), 0.f);
            w.z = fmaxf(fmaf(acc[4 * u + 2], dv0, bb[4 * u + 2]), 0.f);
            w.w = fmaxf(fmaf(acc[4 * u + 3], dv0, bb[4 * u + 3]), 0.f);
            *(float4*)&Bt[g][c * 16 + 4 * u] = w;
        }
    } else {
#pragma unroll
        for (int u = 0; u < 4; ++u)
            *(float4*)&Bt[g][c * 16 + 4 * u] = make_float4(0.f, 0.f, 0.f, 0.f);
    }
    __syncthreads();

    const int tx = t & 15;
    const int ty = t >> 4;
    float a2[4][4] = {{0.f}};
#pragma unroll 2
    for (int k0 = 0; k0 < 64; k0 += 4) {
        float4 x0 = *(const float4*)&Bt[4 * ty + 0][k0];
        float4 x1 = *(const float4*)&Bt[4 * ty + 1][k0];
        float4 x2 = *(const float4*)&Bt[4 * ty + 2][k0];
        float4 x3 = *(const float4*)&Bt[4 * ty + 3][k0];
        float4 w0 = *(const float4*)&Ws2[(k0 + 0) * 64 + 4 * tx];
        float4 w1 = *(const float4*)&Ws2[(k0 + 1) * 64 + 4 * tx];
        float4 w2 = *(const float4*)&Ws2[(k0 + 2) * 64 + 4 * tx];
        float4 w3 = *(const float4*)&Ws2[(k0 + 3) * 64 + 4 * tx];
        const float* xp[4] = {(const float*)&x0, (const float*)&x1,
                              (const float*)&x2, (const float*)&x3};
        const float* wp[4] = {(const float*)&w0, (const float*)&w1,
                              (const float*)&w2, (const float*)&w3};
#pragma unroll
        for (int r = 0; r < 4; ++r)
#pragma unroll
            for (int kk = 0; kk < 4; ++kk) {
                float av = xp[r][kk];
#pragma unroll
                for (int cc = 0; cc < 4; ++cc)
                    a2[r][cc] = fmaf(av, wp[kk][cc], a2[r][cc]);
            }
    }
#pragma unroll
    for (int r = 0; r < 4; ++r) {
        int row = row0 + 4 * ty + r;
        if (row < n) {
            float dv = dinv[row];
            __half2 p01 = __floats2half2_rn(a2[r][0] * dv, a2[r][1] * dv);
            __half2 p23 = __floats2half2_rn(a2[r][2] * dv, a2[r][3] * dv);
            float2 st;
            ((__half2*)&st)[0] = p01;
            ((__half2*)&st)[1] = p23;
            *(float2*)&g2[(size_t)row * 64 + 4 * tx] = st;
        }
    }
}

// ================= K4: aggregate layer2 -> d_out =================
__global__ __launch_bounds__(256) void aggregate2_kernel(
    const __half* __restrict__ hs,
    const int* __restrict__ row_ptr,
    const int* __restrict__ esrc,
    const float* __restrict__ dinv,
    const float* __restrict__ bias,
    float* __restrict__ out, int n) {
    const int v = blockIdx.x * 32 + (threadIdx.x >> 3);
    if (v >= n) return;
    const int c8 = threadIdx.x & 7;
    const float4* __restrict__ hs4 = (const float4*)hs;

    const int beg = row_ptr[v];
    const int end = row_ptr[v + 1];

    float acc[8];
    {
        float4 raw = hs4[(size_t)v * 8 + c8];
        const __half2* hp = (const __half2*)&raw;
#pragma unroll
        for (int q = 0; q < 4; ++q) {
            float2 f = __half22float2(hp[q]);
            acc[2 * q] = f.x; acc[2 * q + 1] = f.y;
        }
    }

    int j = beg;
    for (; j + 4 <= end; j += 4) {
        int s0 = esrc[j], s1 = esrc[j + 1], s2 = esrc[j + 2], s3 = esrc[j + 3];
        float4 r0 = hs4[(size_t)s0 * 8 + c8];
        float4 r1 = hs4[(size_t)s1 * 8 + c8];
        float4 r2 = hs4[(size_t)s2 * 8 + c8];
        float4 r3 = hs4[(size_t)s3 * 8 + c8];
        const __half2* h0 = (const __half2*)&r0;
        const __half2* h1 = (const __half2*)&r1;
        const __half2* h2 = (const __half2*)&r2;
        const __half2* h3 = (const __half2*)&r3;
#pragma unroll
        for (int q = 0; q < 4; ++q) {
            float2 f0 = __half22float2(h0[q]);
            float2 f1 = __half22float2(h1[q]);
            float2 f2 = __half22float2(h2[q]);
            float2 f3 = __half22float2(h3[q]);
            acc[2 * q]     += (f0.x + f1.x) + (f2.x + f3.x);
            acc[2 * q + 1] += (f0.y + f1.y) + (f2.y + f3.y);
        }
    }
    for (; j < end; ++j) {
        int s0 = esrc[j];
        float4 r0 = hs4[(size_t)s0 * 8 + c8];
        const __half2* h0 = (const __half2*)&r0;
#pragma unroll
        for (int q = 0; q < 4; ++q) {
            float2 f0 = __half22float2(h0[q]);
            acc[2 * q] += f0.x;
            acc[2 * q + 1] += f0.y;
        }
    }

    float dv = dinv[v];
    float4 b0 = *(const float4*)(bias + c8 * 8);
    float4 b1v = *(const float4*)(bias + c8 * 8 + 4);
    float4 o0, o1;
    o0.x = fmaf(acc[0], dv, b0.x); o0.y = fmaf(acc[1], dv, b0.y);
    o0.z = fmaf(acc[2], dv, b0.z); o0.w = fmaf(acc[3], dv, b0.w);
    o1.x = fmaf(acc[4], dv, b1v.x); o1.y = fmaf(acc[5], dv, b1v.y);
    o1.z = fmaf(acc[6], dv, b1v.z); o1.w = fmaf(acc[7], dv, b1v.w);
    float4* op = (float4*)(out + (size_t)v * 64 + c8 * 8);
    op[0] = o0;
    op[1] = o1;
}

extern "C" void kernel_launch(void* const* d_in, const int* in_sizes, int n_in,
                              void* d_out, int out_size, void* d_ws, size_t ws_size,
                              hipStream_t stream) {
    const float* x  = (const float*)d_in[0];
    const int*   ei = (const int*)d_in[1];
    const float* W1 = (const float*)d_in[2];
    const float* b1 = (const float*)d_in[3];
    const float* W2 = (const float*)d_in[4];
    const float* b2 = (const float*)d_in[5];
    float* out = (float*)d_out;

    const int C_IN = 128;
    const int n = in_sizes[0] / C_IN;   // 50000 (<= 65536 required)
    const int E = in_sizes[1] / 2;      // 800000
    const int* src = ei;
    const int* dst = ei + E;

    const int nb = (n + 255) >> 8;              // 196 buckets (<= 256)
    const int ngb = (n + 63) / 64;              // gemm tile blocks
    const int ePer = (E + nb - 1) / nb;         // edges per hist/scatter chunk

    // Workspace: dinv | g1 | g2 | row_ptr | S | T | ebuf | esrc
    char* w = (char*)d_ws;
    float*    dinv    = (float*)w;    w += alignup((size_t)n * sizeof(float));
    __half*   g1      = (__half*)w;   w += alignup((size_t)n * C_HID * sizeof(__half));
    __half*   g2      = (__half*)w;   w += alignup((size_t)n * C_HID * sizeof(__half));
    int*      row_ptr = (int*)w;      w += alignup((size_t)(n + 1) * sizeof(int));
    int*      S       = (int*)w;      w += alignup((size_t)nb * nb * sizeof(int));
    int*      T       = (int*)w;      w += alignup((size_t)(nb + 1) * sizeof(int));
    unsigned* ebuf    = (unsigned*)w; w += alignup((size_t)E * sizeof(unsigned));
    int*      esrc    = (int*)w;

    // K1: gemm1 || hist
    gemm1_hist_kernel<128><<<nb + ngb, 256, 0, stream>>>(
        x, W1, dst, g1, S, n, E, ePer, nb);

    // K2: CSR build (launch boundaries as barriers)
    scan_rows_kernel<<<nb, 256, 0, stream>>>(S, T, nb);
    scan_T_kernel<<<1, 256, 0, stream>>>(T, nb);
    scatter_kernel<<<nb, 256, 0, stream>>>(src, dst, E, ePer, S, T, ebuf, nb);
    build_kernel<<<nb, 256, 0, stream>>>(ebuf, T, row_ptr, dinv, esrc, n, nb);

    // K3: aggregate layer1 + gemm2 fused
    agg1_gemm2_kernel<<<ngb, 256, 0, stream>>>(
        g1, row_ptr, esrc, dinv, b1, W2, g2, n);

    // K4: aggregate layer2 -> out
    aggregate2_kernel<<<(n + 31) / 32, 256, 0, stream>>>(
        g2, row_ptr, esrc, dinv, b2, out, n);
}